// Round 1
// baseline (2593.834 us; speedup 1.0000x reference)
//
#include <hip/hip_runtime.h>
#include <math.h>

// Problem constants (match reference)
constexpr int B = 4, C = 64, H = 96, W = 96;
constexpr int KT = 9;           // 3x3 taps
constexpr int OFFC = 18;        // 2*KT offset channels
constexpr int HW = H * W;

// ---------------------------------------------------------------------------
// Kernel 1: offset = conv3x3(x, w_off, pad=1) + b_off
// x:     [B, C, H, W]
// w_off: [18, C, 3, 3]
// off:   [B, 18, H, W]
// One thread per output element.
// ---------------------------------------------------------------------------
__global__ void offset_conv_kernel(const float* __restrict__ x,
                                   const float* __restrict__ w_off,
                                   const float* __restrict__ b_off,
                                   float* __restrict__ off) {
    int idx = blockIdx.x * blockDim.x + threadIdx.x;
    const int total = B * OFFC * HW;
    if (idx >= total) return;

    int w = idx % W;
    int t = idx / W;
    int h = t % H;
    t /= H;
    int oc = t % OFFC;
    int b  = t / OFFC;

    float acc = b_off[oc];
    const float* xb = x + (size_t)b * C * HW;
    const float* wk = w_off + (size_t)oc * C * 9;

    for (int c = 0; c < C; ++c) {
        const float* xc = xb + c * HW;
        const float* wc = wk + c * 9;
        #pragma unroll
        for (int ky = 0; ky < 3; ++ky) {
            int yy = h + ky - 1;
            if (yy < 0 || yy >= H) continue;
            #pragma unroll
            for (int kx = 0; kx < 3; ++kx) {
                int xx = w + kx - 1;
                if (xx < 0 || xx >= W) continue;
                acc = fmaf(xc[yy * W + xx], wc[ky * 3 + kx], acc);
            }
        }
    }
    off[idx] = acc;
}

// ---------------------------------------------------------------------------
// Kernel 2: deformable conv.
// Block = 256 threads = 4 pixels x 64 output channels (one wave per pixel).
// For each tap: lane c computes the bilinear sample for channel c, stages it
// in LDS, then every lane o contracts over the 64 channels with w_dc[o][c][k].
// ---------------------------------------------------------------------------
__device__ __forceinline__ float fetch_x(const float* __restrict__ xc, int y, int x) {
    if (y < 0 || y >= H || x < 0 || x >= W) return 0.0f;
    return xc[y * W + x];
}

__global__ void deform_conv_kernel(const float* __restrict__ x,
                                   const float* __restrict__ off,
                                   const float* __restrict__ w_dc,
                                   const float* __restrict__ b_dc,
                                   float* __restrict__ out) {
    const int lane = threadIdx.x & 63;       // output channel o AND sample channel c
    const int px_id = threadIdx.x >> 6;      // 0..3, pixel within block
    const int pix = blockIdx.x * 4 + px_id;  // global pixel over B*H*W
    // B*H*W = 36864, grid*4 exactly covers it.
    const int w = pix % W;
    int t = pix / W;
    const int h = t % H;
    const int b = t / H;

    __shared__ float smem[4][64];

    const float* xb = x + (size_t)b * C * HW;
    float acc = b_dc[lane];

    #pragma unroll
    for (int k = 0; k < KT; ++k) {
        const int ky = k / 3, kx = k % 3;
        const float dy = off[(((size_t)b * OFFC + 2 * k) * H + h) * W + w];
        const float dx = off[(((size_t)b * OFFC + 2 * k + 1) * H + h) * W + w];
        const float py = (float)(h + ky - 1) + dy;
        const float px = (float)(w + kx - 1) + dx;
        const float y0f = floorf(py);
        const float x0f = floorf(px);
        const float ly = py - y0f;
        const float lx = px - x0f;
        const int y0 = (int)y0f;
        const int x0 = (int)x0f;

        // lane samples its own channel c = lane
        const float* xc = xb + lane * HW;
        const float v00 = fetch_x(xc, y0,     x0);
        const float v01 = fetch_x(xc, y0,     x0 + 1);
        const float v10 = fetch_x(xc, y0 + 1, x0);
        const float v11 = fetch_x(xc, y0 + 1, x0 + 1);
        const float s = v00 * (1.0f - ly) * (1.0f - lx)
                      + v01 * (1.0f - ly) * lx
                      + v10 * ly * (1.0f - lx)
                      + v11 * ly * lx;

        __syncthreads();             // protect smem from previous tap's readers
        smem[px_id][lane] = s;
        __syncthreads();

        // contract over channels: acc += sum_c smem[c] * w_dc[o][c][k]
        const float* wdk = w_dc + (size_t)lane * C * 9 + k;  // stride 9 over c
        #pragma unroll 8
        for (int c2 = 0; c2 < C; ++c2) {
            acc = fmaf(smem[px_id][c2], wdk[c2 * 9], acc);
        }
    }

    out[(((size_t)b * C + lane) * H + h) * W + w] = acc;
}

// ---------------------------------------------------------------------------
extern "C" void kernel_launch(void* const* d_in, const int* in_sizes, int n_in,
                              void* d_out, int out_size, void* d_ws, size_t ws_size,
                              hipStream_t stream) {
    const float* x     = (const float*)d_in[0];
    const float* w_off = (const float*)d_in[1];
    const float* b_off = (const float*)d_in[2];
    const float* w_dc  = (const float*)d_in[3];
    const float* b_dc  = (const float*)d_in[4];
    float* out = (float*)d_out;

    float* off = (float*)d_ws;  // B*18*H*W floats = 2.65 MB

    {
        const int total = B * OFFC * HW;
        const int blk = 256;
        const int grid = (total + blk - 1) / blk;
        offset_conv_kernel<<<grid, blk, 0, stream>>>(x, w_off, b_off, off);
    }
    {
        const int grid = (B * HW) / 4;  // 9216 blocks, 4 pixels each
        deform_conv_kernel<<<grid, 256, 0, stream>>>(x, off, w_dc, b_dc, out);
    }
}

// Round 2
// 315.499 us; speedup vs baseline: 8.2214x; 8.2214x over previous
//
#include <hip/hip_runtime.h>
#include <math.h>

constexpr int B = 4, C = 64, H = 96, W = 96;
constexpr int KT = 9;           // 3x3 taps
constexpr int OFFC = 18;        // 2*KT offset channels
constexpr int HW = H * W;

// ---------------------------------------------------------------------------
// Prep: transpose weights so the hot loops read wave-uniform contiguous runs.
//   wofft[k][c][oc] = w_off[oc][c][k]     (9*64*18)
//   wdct [k][c][o]  = w_dc [o][c][k]      (9*64*64)
// ---------------------------------------------------------------------------
__global__ void prep_weights(const float* __restrict__ w_off,
                             const float* __restrict__ w_dc,
                             float* __restrict__ wofft,
                             float* __restrict__ wdct) {
    int i = blockIdx.x * 256 + threadIdx.x;
    if (i < KT * C * OFFC) {
        int k = i / (C * OFFC);
        int r = i % (C * OFFC);
        int c = r / OFFC;
        int oc = r % OFFC;
        wofft[i] = w_off[(oc * C + c) * KT + k];
    }
    if (i < KT * C * C) {
        int k = i / (C * C);
        int r = i % (C * C);
        int c = r / C;
        int o = r % C;
        wdct[i] = w_dc[(o * C + c) * KT + k];
    }
}

// ---------------------------------------------------------------------------
// Offset conv: thread = pixel, 9 offset channels per thread (2 groups).
// x loads coalesced along w; weights wave-uniform.
// ---------------------------------------------------------------------------
__global__ void offset_conv2(const float* __restrict__ x,
                             const float* __restrict__ wofft,
                             const float* __restrict__ b_off,
                             float* __restrict__ off) {
    const int pix = blockIdx.x * 256 + threadIdx.x;   // 0 .. B*HW-1
    const int ocg = blockIdx.y;                       // 0 or 1
    const int w = pix % W;
    int t = pix / W;
    const int h = t % H;
    const int b_u = __builtin_amdgcn_readfirstlane(t / H);  // uniform per wave

    const float* xb = x + (size_t)b_u * C * HW;

    float acc[9];
    #pragma unroll
    for (int j = 0; j < 9; ++j) acc[j] = b_off[ocg * 9 + j];

    #pragma unroll
    for (int k = 0; k < KT; ++k) {
        const int yy = h + k / 3 - 1;
        const int xx = w + k % 3 - 1;
        const bool valid = (yy >= 0) && (yy < H) && (xx >= 0) && (xx < W);
        const float vf = valid ? 1.0f : 0.0f;
        const int idx = (valid ? yy : 0) * W + (valid ? xx : 0);

        const float* xc = xb;
        const float* wp = wofft + (size_t)k * C * OFFC + ocg * 9;
        #pragma unroll 4
        for (int c = 0; c < C; ++c) {
            const float v = xc[idx] * vf;
            #pragma unroll
            for (int j = 0; j < 9; ++j) acc[j] = fmaf(v, wp[j], acc[j]);
            xc += HW;
            wp += OFFC;
        }
    }

    float* ob = off + ((size_t)b_u * OFFC + ocg * 9) * HW + h * W + w;
    #pragma unroll
    for (int j = 0; j < 9; ++j) ob[j * HW] = acc[j];
}

// ---------------------------------------------------------------------------
// Deformable conv: thread = pixel, 16 output channels per thread (4 groups).
// Bilinear corners computed once per tap, reused for all 64 input channels.
// ---------------------------------------------------------------------------
__global__ void deform_conv2(const float* __restrict__ x,
                             const float* __restrict__ off,
                             const float* __restrict__ wdct,
                             const float* __restrict__ b_dc,
                             float* __restrict__ out) {
    const int pix = blockIdx.x * 256 + threadIdx.x;
    const int og = blockIdx.y * 16;                    // output-channel group
    const int w = pix % W;
    int t = pix / W;
    const int h = t % H;
    const int b_u = __builtin_amdgcn_readfirstlane(t / H);  // uniform per wave

    const float* xb = x + (size_t)b_u * C * HW;

    float acc[16];
    #pragma unroll
    for (int o = 0; o < 16; ++o) acc[o] = b_dc[og + o];

    const float* offb = off + (size_t)b_u * OFFC * HW + h * W + w;

    #pragma unroll
    for (int k = 0; k < KT; ++k) {
        const float dy = offb[(2 * k) * HW];
        const float dx = offb[(2 * k + 1) * HW];
        const float py = (float)(h + k / 3 - 1) + dy;
        const float px = (float)(w + k % 3 - 1) + dx;
        const float y0f = floorf(py);
        const float x0f = floorf(px);
        const float ly = py - y0f;
        const float lx = px - x0f;
        const int y0 = (int)y0f;
        const int x0 = (int)x0f;

        // 4 corners: clamped index + (bilinear weight * validity)
        int ci0, ci1, ci2, ci3;
        float cw0, cw1, cw2, cw3;
        {
            int yi, xi, yc, xc2;
            bool v;
            yi = y0;     xi = x0;
            v = (yi >= 0) && (yi < H) && (xi >= 0) && (xi < W);
            yc = min(max(yi, 0), H - 1); xc2 = min(max(xi, 0), W - 1);
            ci0 = yc * W + xc2; cw0 = v ? (1.0f - ly) * (1.0f - lx) : 0.0f;
            yi = y0;     xi = x0 + 1;
            v = (yi >= 0) && (yi < H) && (xi >= 0) && (xi < W);
            yc = min(max(yi, 0), H - 1); xc2 = min(max(xi, 0), W - 1);
            ci1 = yc * W + xc2; cw1 = v ? (1.0f - ly) * lx : 0.0f;
            yi = y0 + 1; xi = x0;
            v = (yi >= 0) && (yi < H) && (xi >= 0) && (xi < W);
            yc = min(max(yi, 0), H - 1); xc2 = min(max(xi, 0), W - 1);
            ci2 = yc * W + xc2; cw2 = v ? ly * (1.0f - lx) : 0.0f;
            yi = y0 + 1; xi = x0 + 1;
            v = (yi >= 0) && (yi < H) && (xi >= 0) && (xi < W);
            yc = min(max(yi, 0), H - 1); xc2 = min(max(xi, 0), W - 1);
            ci3 = yc * W + xc2; cw3 = v ? ly * lx : 0.0f;
        }

        const float* xc = xb;
        const float* wp = wdct + (size_t)k * C * C + og;
        #pragma unroll 4
        for (int c = 0; c < C; ++c) {
            const float s = xc[ci0] * cw0 + xc[ci1] * cw1
                          + xc[ci2] * cw2 + xc[ci3] * cw3;
            #pragma unroll
            for (int o = 0; o < 16; ++o) acc[o] = fmaf(s, wp[o], acc[o]);
            xc += HW;
            wp += C;
        }
    }

    float* ob = out + ((size_t)b_u * C + og) * HW + h * W + w;
    #pragma unroll
    for (int o = 0; o < 16; ++o) ob[o * HW] = acc[o];
}

// ---------------------------------------------------------------------------
extern "C" void kernel_launch(void* const* d_in, const int* in_sizes, int n_in,
                              void* d_out, int out_size, void* d_ws, size_t ws_size,
                              hipStream_t stream) {
    const float* x     = (const float*)d_in[0];
    const float* w_off = (const float*)d_in[1];
    const float* b_off = (const float*)d_in[2];
    const float* w_dc  = (const float*)d_in[3];
    const float* b_dc  = (const float*)d_in[4];
    float* out = (float*)d_out;

    char* ws = (char*)d_ws;
    float* off   = (float*)ws;                               // B*18*HW = 2.65 MB
    float* wdct  = (float*)(ws + (size_t)B * OFFC * HW * 4); // 147 KB
    float* wofft = (float*)(ws + (size_t)B * OFFC * HW * 4 + (size_t)KT * C * C * 4);

    {   // weight transpose (covers both, max size KT*C*C = 36864)
        prep_weights<<<144, 256, 0, stream>>>(w_off, w_dc, wofft, wdct);
    }
    {   // offset conv: 144 pixel-tiles x 2 oc-groups
        dim3 grid(144, 2);
        offset_conv2<<<grid, 256, 0, stream>>>(x, wofft, b_off, off);
    }
    {   // deformable conv: 144 pixel-tiles x 4 o-groups
        dim3 grid(144, 4);
        deform_conv2<<<grid, 256, 0, stream>>>(x, off, wdct, b_dc, out);
    }
}